// Round 4
// 1155.743 us; speedup vs baseline: 1.0819x; 1.0819x over previous
//
#include <hip/hip_runtime.h>

typedef unsigned short u16;
typedef __bf16 bf16x8 __attribute__((ext_vector_type(8)));
typedef float f32x4 __attribute__((ext_vector_type(4)));

#define GAS __attribute__((address_space(1)))
#define LAS __attribute__((address_space(3)))

__device__ __forceinline__ void async_copy16(const void* g, void* l) {
    __builtin_amdgcn_global_load_lds((GAS void*)g, (LAS void*)l, 16, 0, 0);
}

__device__ __forceinline__ u16 f2bf(float f) {
    unsigned int u = __float_as_uint(f);
    u = (u + 0x7fffu + ((u >> 16) & 1u)) >> 16;
    return (u16)u;
}
__device__ __forceinline__ float bf2f(u16 h) {
    return __uint_as_float(((unsigned int)h) << 16);
}

__device__ __forceinline__ void store_val(float* p, float v) { *p = v; }
__device__ __forceinline__ void store_val(u16* p, float v) { *p = f2bf(v); }

// ---------------------------------------------------------------------------
// GEMM: C[m,n] = alpha * sum_k A[m,k] * Bt[n,k]  (+ bias[n]) (+ Res[m,n])
// A: bf16 [M,K] lda; Bt: bf16 [N,K] ldb; C: OutT [M,N] ldc.
// M,N multiples of 128; K multiple of 32. blockDim=256, grid=(N/128, M/128, batch)
// m97 structure: 128x128 tile, BK=32, global_load_lds(16B), 16x16x32 bf16 MFMA.
// ---------------------------------------------------------------------------
template <typename OutT, bool ADD_RES, bool ADD_BIAS>
__global__ void gemm_bt(const u16* __restrict__ A, long sA,
                        const u16* __restrict__ Bt, long sB,
                        OutT* __restrict__ C, long sC,
                        const u16* __restrict__ Res,
                        const float* __restrict__ bias,
                        int K, int lda, int ldb, int ldc, float alpha) {
    constexpr int BM = 128, BN = 128, BK = 32;
    __shared__ u16 As[BM * BK];
    __shared__ u16 Bs[BN * BK];

    const int tid  = threadIdx.x;
    const int lane = tid & 63;
    const int wid  = tid >> 6;
    const long bm  = (long)blockIdx.y * BM;
    const long bn  = (long)blockIdx.x * BN;
    const long z   = blockIdx.z;

    A  += z * sA;
    Bt += z * sB;
    C  += z * sC;
    const u16* R = Res + z * sC;  // only valid layout when ADD_RES

    // staging: thread t -> rows t/4 and t/4+64, 16B chunk (t&3)*8 within BK row
    const int srow = tid >> 2;
    const int scol = (tid & 3) * 8;
    const u16* ag0 = A + (bm + srow) * (long)lda + scol;
    const u16* ag1 = A + (bm + srow + 64) * (long)lda + scol;
    const u16* bg0 = Bt + (bn + srow) * (long)ldb + scol;
    const u16* bg1 = Bt + (bn + srow + 64) * (long)ldb + scol;
    u16* al0 = &As[srow * BK + scol];
    u16* al1 = &As[(srow + 64) * BK + scol];
    u16* bl0 = &Bs[srow * BK + scol];
    u16* bl1 = &Bs[(srow + 64) * BK + scol];

    const int wm   = (wid & 1) * 64;
    const int wn   = (wid >> 1) * 64;
    const int frow = lane & 15;
    const int fk   = (lane >> 4) * 8;

    f32x4 acc[4][4];
#pragma unroll
    for (int i = 0; i < 4; i++)
#pragma unroll
        for (int j = 0; j < 4; j++) acc[i][j] = f32x4{0.f, 0.f, 0.f, 0.f};

    for (int k0 = 0; k0 < K; k0 += BK) {
        async_copy16(ag0 + k0, al0);
        async_copy16(ag1 + k0, al1);
        async_copy16(bg0 + k0, bl0);
        async_copy16(bg1 + k0, bl1);
        __syncthreads();  // drains vmcnt before barrier

        bf16x8 af[4], bfv[4];
#pragma unroll
        for (int i = 0; i < 4; i++)
            af[i] = *(const bf16x8*)&As[(wm + i * 16 + frow) * BK + fk];
#pragma unroll
        for (int j = 0; j < 4; j++)
            bfv[j] = *(const bf16x8*)&Bs[(wn + j * 16 + frow) * BK + fk];
#pragma unroll
        for (int i = 0; i < 4; i++)
#pragma unroll
            for (int j = 0; j < 4; j++)
                acc[i][j] = __builtin_amdgcn_mfma_f32_16x16x32_bf16(
                    af[i], bfv[j], acc[i][j], 0, 0, 0);
        __syncthreads();
    }

    // epilogue: C/D layout col=lane&15, row=(lane>>4)*4+reg
    const int r0 = (lane >> 4) * 4;
#pragma unroll
    for (int i = 0; i < 4; i++) {
#pragma unroll
        for (int j = 0; j < 4; j++) {
            const long col = bn + wn + j * 16 + frow;
            float badd = 0.f;
            if constexpr (ADD_BIAS) badd = bias[col];
#pragma unroll
            for (int r = 0; r < 4; r++) {
                const long row = bm + wm + i * 16 + r0 + r;
                float v = acc[i][j][r] * alpha + badd;
                if constexpr (ADD_RES) v += bf2f(R[row * (long)ldc + col]);
                store_val(&C[row * (long)ldc + col], v);
            }
        }
    }
}

// ---------------------------------------------------------------------------
// 256x256 8-wave counted-vmcnt GEMM (T1+T2+T3+T4+T5), f32 out (+bias), NT store.
// C[m,n] = sum_k A[m,k]*Bt[n,k] + bias[n].  M,N mult of 256, K mult of 64 (>=128).
// blockDim=512 (8 waves, 2Mx4N), grid = 1D (M/256)*(N/256) blocks.
// Dynamic LDS 128 KiB: 8 slabs of 16KB = [buf(2)][mat A/B][kk(2)] x [256 rows][32 cols] bf16.
// Slab swizzle (rows are 64B): chunk16B ^= (row>>1)&3  -> <=2-way bank aliasing.
// Staging: global_load_lds 16B, linear LDS dest, PRE-SWIZZLED global source.
// Schedule: 2 phases per K-tile; phase(t,kk0) prefetches tile t+1's kk1 slabs,
// phase(t,kk1) prefetches tile t+2's kk0 slabs, then s_waitcnt vmcnt(4) (never 0
// in main loop).  Slab X of tile t+2 is only staged in the phase AFTER the phase
// that consumed slab X of tile t, with an s_barrier in between -> race-free.
// ---------------------------------------------------------------------------
#define GPHASE(buf, kk, VM, ...)                                              \
    {                                                                         \
        const u16* pa = lA + (((buf) * 4 + (kk)) << 13);                      \
        const u16* pb = lB + (((buf) * 4 + 2 + (kk)) << 13);                  \
        bf16x8 af[8], bv[4];                                                  \
        _Pragma("unroll") for (int i_ = 0; i_ < 8; i_++)                      \
            af[i_] = *(const bf16x8*)(pa + i_ * 512);                         \
        _Pragma("unroll") for (int j_ = 0; j_ < 4; j_++)                      \
            bv[j_] = *(const bf16x8*)(pb + j_ * 512);                         \
        __VA_ARGS__;                                                          \
        asm volatile("" ::: "memory");                                        \
        __builtin_amdgcn_s_barrier();                                         \
        __builtin_amdgcn_s_setprio(1);                                        \
        _Pragma("unroll") for (int i_ = 0; i_ < 8; i_++)                      \
            _Pragma("unroll") for (int j_ = 0; j_ < 4; j_++)                  \
                acc[i_][j_] = __builtin_amdgcn_mfma_f32_16x16x32_bf16(        \
                    af[i_], bv[j_], acc[i_][j_], 0, 0, 0);                    \
        __builtin_amdgcn_s_setprio(0);                                        \
        VM;                                                                   \
        asm volatile("" ::: "memory");                                        \
        __builtin_amdgcn_s_barrier();                                         \
        asm volatile("" ::: "memory");                                        \
    }

template <bool ADD_BIAS>
__global__ __launch_bounds__(512, 2)
void gemm256_bt(const u16* __restrict__ A, const u16* __restrict__ Bt,
                float* __restrict__ C, const float* __restrict__ bias,
                int K, int lda, int ldb, int ldc, int tilesN) {
    extern __shared__ u16 lds[];  // 8 slabs x 8192 elems (16KB) = 128 KiB

    const int tid  = threadIdx.x;
    const int lane = tid & 63;
    const int wid  = tid >> 6;
    const int wr   = wid >> 2;  // 0..1
    const int wc   = wid & 3;   // 0..3

    // T1: bijective XCD swizzle (valid when nwg % 8 == 0)
    const int bid = (int)blockIdx.x;
    const int nwg = (int)gridDim.x;
    int wgid = bid;
    if ((nwg & 7) == 0) wgid = (bid & 7) * (nwg >> 3) + (bid >> 3);
    const long bm = (long)(wgid / tilesN) * 256;
    const long bn = (long)(wgid % tilesN) * 256;

    // staging: thread t covers slab-linear bytes t*16 (+8KB for second half).
    // linear row = t>>2; source chunk pre-swizzled: (t&3) ^ ((t>>3)&3).
    const int srow  = tid >> 2;
    const int schk  = ((tid & 3) ^ ((tid >> 3) & 3)) << 3;  // source col (elems)
    const u16* Ag = A + (bm + srow) * (long)lda + schk;
    const u16* Bg = Bt + (bn + srow) * (long)ldb + schk;
    u16* ldsw = lds + tid * 8;

    auto stage2 = [&](int buf, int kk, int t) {
        const long ko = (long)t * 64 + kk * 32;
        const u16* a  = Ag + ko;
        const u16* b  = Bg + ko;
        u16* dA = ldsw + (((buf * 4) + kk) << 13);
        u16* dB = ldsw + (((buf * 4) + 2 + kk) << 13);
        async_copy16(a, dA);
        async_copy16(a + (long)lda * 128, dA + 4096);
        async_copy16(b, dB);
        async_copy16(b + (long)ldb * 128, dB + 4096);
    };

    // fragment read bases: row = (wr*128 | wc*64) + i*16 + (lane&15),
    // chunk = (lane>>4) ^ ((row>>1)&3)  (= (lane>>4) ^ ((lane>>1)&3), row-invariant)
    const int fr    = lane & 15;
    const int cSwzE = (((lane >> 4) ^ ((lane >> 1) & 3)) << 3);
    const u16* lA = lds + (wr * 128 + fr) * 32 + cSwzE;
    const u16* lB = lds + (wc * 64 + fr) * 32 + cSwzE;

    f32x4 acc[8][4];
#pragma unroll
    for (int i = 0; i < 8; i++)
#pragma unroll
        for (int j = 0; j < 4; j++) acc[i][j] = f32x4{0.f, 0.f, 0.f, 0.f};

    const int NT = K >> 6;  // K-tiles of 64 (requires NT >= 2)

    // prologue: tile0 fully, tile1 kk0; leave tile1-kk0 (4 loads) in flight.
    stage2(0, 0, 0);
    stage2(0, 1, 0);
    stage2(1, 0, 1);
    asm volatile("s_waitcnt vmcnt(4)" ::: "memory");
    __builtin_amdgcn_s_barrier();
    asm volatile("" ::: "memory");

    int t = 0;
    for (; t < NT - 2; ++t) {
        const int buf = t & 1;
        GPHASE(buf, 0, , stage2(buf ^ 1, 1, t + 1));
        GPHASE(buf, 1, asm volatile("s_waitcnt vmcnt(4)" ::: "memory"),
               stage2(buf, 0, t + 2));
    }
    {   // t == NT-2
        const int buf = t & 1;
        GPHASE(buf, 0, , stage2(buf ^ 1, 1, t + 1));
        GPHASE(buf, 1, asm volatile("s_waitcnt vmcnt(0)" ::: "memory"), );
        // t == NT-1
        const int buf2 = buf ^ 1;
        GPHASE(buf2, 0, , );
        GPHASE(buf2, 1, , );
    }

    // epilogue: C/D layout col=lane&15, row=(lane>>4)*4+reg.  NT stores: keep the
    // 524MB f32 write stream from evicting the L3-resident A/B panels.
    const int r0 = (lane >> 4) * 4;
#pragma unroll
    for (int j = 0; j < 4; j++) {
        const long col = bn + wc * 64 + j * 16 + fr;
        float badd = 0.f;
        if constexpr (ADD_BIAS) badd = bias[col];
#pragma unroll
        for (int i = 0; i < 8; i++) {
#pragma unroll
            for (int r = 0; r < 4; r++) {
                const long row = bm + wr * 128 + i * 16 + r0 + r;
                __builtin_nontemporal_store(acc[i][j][r] + badd,
                                            &C[row * (long)ldc + col]);
            }
        }
    }
}

// f32 [R,C] -> bf16 [C,R] (transpose + convert), 32x32 LDS tiles
__global__ void transpose_f32_bf16(const float* __restrict__ in, u16* __restrict__ out,
                                   int R, int C) {
    __shared__ float tile[32][33];
    const int bx = blockIdx.x * 32;  // col base
    const int by = blockIdx.y * 32;  // row base
    const int tx = threadIdx.x, ty = threadIdx.y;
#pragma unroll
    for (int i = 0; i < 32; i += 8)
        tile[ty + i][tx] = in[(long)(by + ty + i) * C + (bx + tx)];
    __syncthreads();
#pragma unroll
    for (int i = 0; i < 32; i += 8)
        out[(long)(bx + ty + i) * R + (by + tx)] = f2bf(tile[tx][ty + i]);
}

// h[row,:] = bf16(emb[x[row],:] + pos[row%S,:]); H=1024, block=256 (x4 f32)
__global__ void embed_kernel(const int* __restrict__ x, const float* __restrict__ emb,
                             const float* __restrict__ pos, u16* __restrict__ h, int S) {
    const int row = blockIdx.x;
    const int s   = row % S;
    const int tok = x[row];
    const int t   = threadIdx.x;
    const float4 e = ((const float4*)(emb + (long)tok * 1024))[t];
    const float4 p = ((const float4*)(pos + (long)s * 1024))[t];
    unsigned int lo = (unsigned)f2bf(e.x + p.x) | ((unsigned)f2bf(e.y + p.y) << 16);
    unsigned int hi = (unsigned)f2bf(e.z + p.z) | ((unsigned)f2bf(e.w + p.w) << 16);
    ((uint2*)(h + (long)row * 1024))[t] = make_uint2(lo, hi);
}

// causal softmax: row = b*S+s, valid cols [0, s]; scores f32 -> attn bf16
__global__ void softmax_causal(const float* __restrict__ sc, u16* __restrict__ attn,
                               int S, float scale) {
    const int row = blockIdx.x;
    const int s   = row % S;
    const int n   = s + 1;
    const float* r = sc + (long)row * S;
    u16* o = attn + (long)row * S;
    const int tid = threadIdx.x, lane = tid & 63, wid = tid >> 6;
    __shared__ float red[4];

    float mx = -3.0e38f;
    for (int i = tid; i < n; i += 256) mx = fmaxf(mx, r[i]);
#pragma unroll
    for (int off = 32; off; off >>= 1) mx = fmaxf(mx, __shfl_xor(mx, off, 64));
    if (lane == 0) red[wid] = mx;
    __syncthreads();
    mx = fmaxf(fmaxf(red[0], red[1]), fmaxf(red[2], red[3])) * scale;

    float sum = 0.f;
    for (int i = tid; i < n; i += 256) sum += __expf(r[i] * scale - mx);
#pragma unroll
    for (int off = 32; off; off >>= 1) sum += __shfl_xor(sum, off, 64);
    __syncthreads();
    if (lane == 0) red[wid] = sum;
    __syncthreads();
    const float inv = 1.f / (red[0] + red[1] + red[2] + red[3]);

    for (int i = tid; i < n; i += 256) o[i] = f2bf(__expf(r[i] * scale - mx) * inv);
    for (int i = n + tid; i < S; i += 256) o[i] = 0;
}

extern "C" void kernel_launch(void* const* d_in, const int* in_sizes, int n_in,
                              void* d_out, int out_size, void* d_ws, size_t ws_size,
                              hipStream_t stream) {
    const int B = 2, S = 2048, H = 1024, V = 32000;
    const int* x     = (const int*)d_in[0];
    const float* emb = (const float*)d_in[1];
    const float* pos = (const float*)d_in[2];
    const float* Wk  = (const float*)d_in[3];  // NOTE: setup_inputs order: Wk before Wq
    const float* Wq  = (const float*)d_in[4];
    const float* Wv  = (const float*)d_in[5];
    const float* Wo  = (const float*)d_in[6];
    const float* bo  = (const float*)d_in[7];
    float* out = (float*)d_out;

    char* ws = (char*)d_ws;
    u16* h_bf   = (u16*)(ws + 0);           //  8 MB  [4096,1024]
    u16* WqT    = (u16*)(ws + 8388608);     //  2 MB  [1024,1024]
    u16* WkT    = (u16*)(ws + 10485760);    //  2 MB
    u16* WvT    = (u16*)(ws + 12582912);    //  2 MB
    u16* WoT    = (u16*)(ws + 14680064);    // 65.5MB [32000,1024]
    u16* q_bf   = (u16*)(ws + 80216064);    //  8 MB  [4096,1024]
    u16* k_bf   = (u16*)(ws + 88604672);    //  8 MB
    u16* vT_bf  = (u16*)(ws + 96993280);    //  8 MB  [1024,4096]
    float* scor = (float*)(ws + 105381888); // 33.5MB [2,2048,2048]
    u16* attn   = (u16*)(ws + 138936320);   // 16.8MB [2,2048,2048]
    u16* z_bf   = (u16*)(ws + 155713536);   //  8 MB  [4096,1024]  (total ~164MB)

    static int lds_opt_in = 0;
    if (!lds_opt_in) {
        hipFuncSetAttribute((const void*)gemm256_bt<true>,
                            hipFuncAttributeMaxDynamicSharedMemorySize, 131072);
        lds_opt_in = 1;
    }

    dim3 ttb(32, 8);
    transpose_f32_bf16<<<dim3(32, 32), ttb, 0, stream>>>(Wq, WqT, H, H);
    transpose_f32_bf16<<<dim3(32, 32), ttb, 0, stream>>>(Wk, WkT, H, H);
    transpose_f32_bf16<<<dim3(32, 32), ttb, 0, stream>>>(Wv, WvT, H, H);
    transpose_f32_bf16<<<dim3(V / 32, 32), ttb, 0, stream>>>(Wo, WoT, H, V);

    embed_kernel<<<B * S, 256, 0, stream>>>(x, emb, pos, h_bf, S);

    // q = h @ Wq  -> [4096,1024]
    gemm_bt<u16, false, false><<<dim3(8, 32, 1), 256, 0, stream>>>(
        h_bf, 0, WqT, 0, q_bf, 0, nullptr, nullptr, H, H, H, H, 1.0f);
    // k = h @ Wk
    gemm_bt<u16, false, false><<<dim3(8, 32, 1), 256, 0, stream>>>(
        h_bf, 0, WkT, 0, k_bf, 0, nullptr, nullptr, H, H, H, H, 1.0f);
    // vT = Wv^T @ h^T -> [1024, 4096]
    gemm_bt<u16, false, false><<<dim3(32, 8, 1), 256, 0, stream>>>(
        WvT, 0, h_bf, 0, vT_bf, 0, nullptr, nullptr, H, H, H, B * S, 1.0f);

    // scores[b] = q[b] @ k[b]^T  -> f32 [2048,2048] per batch
    gemm_bt<float, false, false><<<dim3(16, 16, B), 256, 0, stream>>>(
        q_bf, (long)S * H, k_bf, (long)S * H, scor, (long)S * S,
        nullptr, nullptr, H, H, H, S, 1.0f);

    softmax_causal<<<B * S, 256, 0, stream>>>(scor, attn, S, 0.03125f);

    // z[b] = attn[b] @ v[b] + h[b]  -> bf16 [2048,1024] per batch
    gemm_bt<u16, true, false><<<dim3(8, 16, B), 256, 0, stream>>>(
        attn, (long)S * S, vT_bf, (long)S, z_bf, (long)S * H,
        h_bf, nullptr, S, S, B * S, H, 1.0f);

    // out = z @ Wo + bo -> f32 [4096, 32000]; 256^2 8-wave counted-vmcnt kernel
    gemm256_bt<true><<<dim3((V / 256) * (4096 / 256), 1, 1), 512, 131072, stream>>>(
        z_bf, WoT, out, bo, H, H, H, V, V / 256);
}